// Round 9
// baseline (260.562 us; speedup 1.0000x reference)
//
#include <hip/hip_runtime.h>
#include <hip/hip_bf16.h>
#include <math.h>

#define H 256
#define BQ 1024
#define NPOOL 32768
#define MAXN 64

#define TRANS_BLOCKS 32    // 2 matrices x 16 tiles of 64x64
#define QPROJ_BLOCKS 256   // BQ/4

#define KREP 8  // measurement: kvproj internal replication
#define AREP 8  // measurement: attn internal replication

typedef __attribute__((ext_vector_type(8))) short short8;
typedef __attribute__((ext_vector_type(8))) unsigned short ushort8v;
typedef __attribute__((ext_vector_type(4))) float f32x4;

__device__ __forceinline__ unsigned short f2bf(float f) {
  unsigned int u = __float_as_uint(f);
  unsigned int r = (u + 0x7fffu + ((u >> 16) & 1u)) >> 16;
  return (unsigned short)r;
}
__device__ __forceinline__ float b2f(unsigned short u) {
  return __uint_as_float((unsigned int)u << 16);
}
__device__ __forceinline__ unsigned int cvt_pk_bf16(float a, float b) {
  unsigned int r;
  asm("v_cvt_pk_bf16_f32 %0, %1, %2" : "=v"(r) : "v"(a), "v"(b));
  return r;
}
__device__ __forceinline__ void gload16(const void* g, void* l) {
  __builtin_amdgcn_global_load_lds(
      (const __attribute__((address_space(1))) unsigned int*)g,
      (__attribute__((address_space(3))) unsigned int*)l, 16, 0, 0);
}

// ---------------------------------------------------------------------------
// prep: [0,32) transpose Wk/Wv->bf16 | [32,288) qproj (4 rows/block)
// (unchanged from r8)
// ---------------------------------------------------------------------------
__global__ __launch_bounds__(256) void prep_kernel(
    const float* __restrict__ Wk, const float* __restrict__ Wv,
    unsigned short* __restrict__ WkT, unsigned short* __restrict__ WvT,
    const float* __restrict__ enc, const float* __restrict__ Wq,
    const float* __restrict__ bq, float* __restrict__ qbuf) {
  __shared__ float smem[64 * 65];
  const int b = blockIdx.x;
  const int t = threadIdx.x;

  if (b < TRANS_BLOCKS) {
    const float* W = (b & 16) ? Wv : Wk;
    unsigned short* WT = (b & 16) ? WvT : WkT;
    const int tile = b & 15;
    const int k0 = (tile >> 2) * 64, c0 = (tile & 3) * 64;
    const int tx = t & 63, ty = t >> 6;
    float (*ls)[65] = (float(*)[65])smem;
#pragma unroll
    for (int kk = 0; kk < 16; ++kk)
      ls[tx][kk * 4 + ty] = W[(size_t)(k0 + kk * 4 + ty) * H + c0 + tx];
    __syncthreads();
#pragma unroll
    for (int cc = 0; cc < 16; ++cc) {
      const int c = cc * 4 + ty;
      WT[(size_t)(c0 + c) * H + k0 + tx] = f2bf(ls[c][tx]);
    }
  } else {
    const int bb = b - TRANS_BLOCKS;
    const int row0 = bb * 4;
    float (*xs)[H] = (float(*)[H])smem;
    {
      float4 v = *(const float4*)(enc + (size_t)(row0 + (t >> 6)) * H + (t & 63) * 4);
      *(float4*)(&xs[t >> 6][(t & 63) * 4]) = v;
    }
    __syncthreads();
    float acc[4] = {0.f, 0.f, 0.f, 0.f};
#pragma unroll 4
    for (int k = 0; k < H; ++k) {
      const float w = Wq[(size_t)k * H + t];
#pragma unroll
      for (int r = 0; r < 4; ++r) acc[r] = fmaf(xs[r][k], w, acc[r]);
    }
    const float bias = bq[t];
#pragma unroll
    for (int r = 0; r < 4; ++r)
      qbuf[(size_t)(row0 + r) * H + t] = fmaxf(acc[r] + bias, 0.f) * 0.0625f;
  }
}

// ---------------------------------------------------------------------------
// kvproj: r8 body, replicated KREP times internally (measurement).
// Each rep recomputes and rewrites identical K/V.
// ---------------------------------------------------------------------------
__global__ __launch_bounds__(256) void kvproj_kernel(
    const float* __restrict__ soc,
    const unsigned short* __restrict__ WkT,
    const unsigned short* __restrict__ WvT,
    const float* __restrict__ bk, const float* __restrict__ bv,
    unsigned short* __restrict__ kout, unsigned short* __restrict__ vout) {
  __shared__ __align__(16) char LDSb[98304];
  const int t = threadIdx.x;
  const int lane = t & 63, wid = t >> 6;
  const int bid = blockIdx.x;
  const int bx = ((bid >> 4) << 3) | (bid & 7);
  const int by = (bid >> 3) & 1;
  const int brow = bx * 128;
  const int col0 = by * 128;

  const int srow = t >> 3;
  const int slin = t & 7;
  const int arow = t >> 1;
  const int sbase = (t & 1) * 4;

  const int wr = wid >> 1, wc = wid & 1;

  float4 av[8];
  const float* asrc = soc + (size_t)(brow + arow) * H + sbase * 8;

#define AREG_LOAD(kt)                                                 \
  {                                                                   \
    const float* p_ = asrc + (kt)*64;                                 \
    _Pragma("unroll") for (int s = 0; s < 4; ++s) {                   \
      av[2 * s] = *(const float4*)(p_ + s * 8);                       \
      av[2 * s + 1] = *(const float4*)(p_ + s * 8 + 4);               \
    }                                                                 \
  }
#define STAGE_B(kt, pb)                                               \
  {                                                                   \
    const int k0_ = (kt)*64;                                          \
    char* bk_ = LDSb + 32768 + (pb)*16384;                            \
    char* bv_ = LDSb + 65536 + (pb)*16384;                            \
    _Pragma("unroll") for (int c = 0; c < 4; ++c) {                   \
      const int row_ = c * 32 + srow;                                 \
      const int ssrc_ = slin ^ (row_ & 7);                            \
      gload16(WkT + (size_t)(col0 + row_) * H + k0_ + ssrc_ * 8,      \
              bk_ + c * 4096 + t * 16);                               \
      gload16(WvT + (size_t)(col0 + row_) * H + k0_ + ssrc_ * 8,      \
              bv_ + c * 4096 + t * 16);                               \
    }                                                                 \
  }
#define AWRITE(pb)                                                    \
  {                                                                   \
    char* ab_ = LDSb + (pb)*16384;                                    \
    _Pragma("unroll") for (int s = 0; s < 4; ++s) {                   \
      uint4 p;                                                        \
      p.x = cvt_pk_bf16(av[2 * s].x, av[2 * s].y);                    \
      p.y = cvt_pk_bf16(av[2 * s].z, av[2 * s].w);                    \
      p.z = cvt_pk_bf16(av[2 * s + 1].x, av[2 * s + 1].y);            \
      p.w = cvt_pk_bf16(av[2 * s + 1].z, av[2 * s + 1].w);            \
      *(uint4*)(ab_ + arow * 128 + ((sbase + s) ^ (arow & 7)) * 16) = p; \
    }                                                                 \
  }

#pragma unroll 1
  for (int rep = 0; rep < KREP; ++rep) {
    f32x4 accK[4][4], accV[4][4];
#pragma unroll
    for (int m = 0; m < 4; ++m)
#pragma unroll
      for (int n = 0; n < 4; ++n) { accK[m][n] = (f32x4)0.f; accV[m][n] = (f32x4)0.f; }

    // prologue: tile 0
    AREG_LOAD(0);
    STAGE_B(0, 0);
    asm volatile("s_waitcnt vmcnt(8)" ::: "memory");
    AWRITE(0);

#pragma unroll
    for (int kt = 0; kt < 4; ++kt) {
      const int cur = kt & 1;
      if (kt < 3) {
        AREG_LOAD(kt + 1);
        STAGE_B(kt + 1, cur ^ 1);
        asm volatile("s_waitcnt vmcnt(16)" ::: "memory");
      } else {
        asm volatile("s_waitcnt vmcnt(0)" ::: "memory");
      }
      asm volatile("s_waitcnt lgkmcnt(0)" ::: "memory");
      __builtin_amdgcn_s_barrier();
      const char* Ab = LDSb + cur * 16384;
      const char* Bkb = LDSb + 32768 + cur * 16384;
      const char* Bvb = LDSb + 65536 + cur * 16384;
#pragma unroll
      for (int kk = 0; kk < 2; ++kk) {
        short8 af[4], bkf[4], bvf[4];
#pragma unroll
        for (int m = 0; m < 4; ++m) {
          const int ar = wr * 64 + m * 16 + (lane & 15);
          const int sl = (kk * 4 + (lane >> 4)) ^ (ar & 7);
          af[m] = *(const short8*)(Ab + ar * 128 + sl * 16);
        }
#pragma unroll
        for (int n = 0; n < 4; ++n) {
          const int br = wc * 64 + n * 16 + (lane & 15);
          const int sl = (kk * 4 + (lane >> 4)) ^ (br & 7);
          bkf[n] = *(const short8*)(Bkb + br * 128 + sl * 16);
          bvf[n] = *(const short8*)(Bvb + br * 128 + sl * 16);
        }
#pragma unroll
        for (int m = 0; m < 4; ++m)
#pragma unroll
          for (int n = 0; n < 4; ++n) {
            accK[m][n] = __builtin_amdgcn_mfma_f32_16x16x32_bf16(
                af[m], bkf[n], accK[m][n], 0, 0, 0);
            accV[m][n] = __builtin_amdgcn_mfma_f32_16x16x32_bf16(
                af[m], bvf[n], accV[m][n], 0, 0, 0);
          }
      }
      if (kt < 3) {
        asm volatile("s_waitcnt vmcnt(8)" ::: "memory");
        AWRITE(cur ^ 1);
      }
      __builtin_amdgcn_s_barrier();
    }

    float bkn[4], bvn[4];
#pragma unroll
    for (int n = 0; n < 4; ++n) {
      const int col = col0 + wc * 64 + n * 16 + (lane & 15);
      bkn[n] = bk[col]; bvn[n] = bv[col];
    }
#pragma unroll
    for (int m = 0; m < 4; ++m)
#pragma unroll
      for (int n = 0; n < 4; ++n) {
        const int col = col0 + wc * 64 + n * 16 + (lane & 15);
#pragma unroll
        for (int r = 0; r < 4; ++r) {
          const int row = brow + wr * 64 + m * 16 + (lane >> 4) * 4 + r;
          kout[(size_t)row * H + col] = f2bf(fmaxf(accK[m][n][r] + bkn[n], 0.f));
          vout[(size_t)row * H + col] = f2bf(fmaxf(accV[m][n][r] + bvn[n], 0.f));
        }
      }
    // all waves finish epilogue before next rep re-stages half 0
    __builtin_amdgcn_s_barrier();
  }
#undef AREG_LOAD
#undef STAGE_B
#undef AWRITE
}

// ---------------------------------------------------------------------------
// attn: r8 body, replicated AREP times internally (measurement).
// ---------------------------------------------------------------------------
__global__ __launch_bounds__(256) void attn_kernel(
    const float* __restrict__ qb, const unsigned short* __restrict__ kb,
    const unsigned short* __restrict__ vb, const int* __restrict__ starts,
    const int* __restrict__ ends, float* __restrict__ out) {
  __shared__ float sc[MAXN];
  const int row = blockIdx.x, t = threadIdx.x;
  const int lane = t & 63, wave = t >> 6;
  const int start = starts[row];
  const int len = ends[row] - start;  // 1..64

  const int qp = (lane & 31) * 8;
  const float4 qv0 = *(const float4*)(qb + (size_t)row * H + qp);
  const float4 qv1 = *(const float4*)(qb + (size_t)row * H + qp + 4);

#pragma unroll 1
  for (int rep = 0; rep < AREP; ++rep) {
    __syncthreads();  // prev rep's PV done before sc overwritten

    for (int jj = wave * 2; jj < len; jj += 8) {
      const int j0 = jj + (lane >> 5);
      if (j0 < len) {
        const ushort8v k8 =
            *(const ushort8v*)(kb + (size_t)(start + j0) * H + qp);
        float s = qv0.x * b2f(k8[0]) + qv0.y * b2f(k8[1]) +
                  qv0.z * b2f(k8[2]) + qv0.w * b2f(k8[3]) +
                  qv1.x * b2f(k8[4]) + qv1.y * b2f(k8[5]) +
                  qv1.z * b2f(k8[6]) + qv1.w * b2f(k8[7]);
#pragma unroll
        for (int off = 16; off; off >>= 1) s += __shfl_xor(s, off, 64);
        if ((lane & 31) == 0) sc[j0] = s;
      }
    }
    __syncthreads();

    if (t < 64) {
      const float x = (t < len) ? sc[t] : -INFINITY;
      float m = x;
#pragma unroll
      for (int off = 32; off; off >>= 1) m = fmaxf(m, __shfl_xor(m, off, 64));
      const float p = (t < len) ? __expf(x - m) : 0.f;
      float ssum = p;
#pragma unroll
      for (int off = 32; off; off >>= 1) ssum += __shfl_xor(ssum, off, 64);
      sc[t] = p / ssum;
    }
    __syncthreads();

    const unsigned short* vp = vb + (size_t)start * H + t;
    float a0 = 0.f, a1 = 0.f, a2 = 0.f, a3 = 0.f;
    int j = 0;
    for (; j + 3 < len; j += 4) {
      a0 = fmaf(sc[j + 0], b2f(vp[(size_t)(j + 0) * H]), a0);
      a1 = fmaf(sc[j + 1], b2f(vp[(size_t)(j + 1) * H]), a1);
      a2 = fmaf(sc[j + 2], b2f(vp[(size_t)(j + 2) * H]), a2);
      a3 = fmaf(sc[j + 3], b2f(vp[(size_t)(j + 3) * H]), a3);
    }
    for (; j < len; ++j) a0 = fmaf(sc[j], b2f(vp[(size_t)j * H]), a0);
    out[(size_t)row * H + t] = (a0 + a1) + (a2 + a3);
  }
}

// ---------------------------------------------------------------------------
extern "C" void kernel_launch(void* const* d_in, const int* in_sizes, int n_in,
                              void* d_out, int out_size, void* d_ws,
                              size_t ws_size, hipStream_t stream) {
  (void)in_sizes; (void)n_in; (void)out_size; (void)ws_size;
  const float* enc = (const float*)d_in[0];
  const float* soc = (const float*)d_in[1];
  const int* starts = (const int*)d_in[2];
  const int* ends = (const int*)d_in[3];
  const float* Wq = (const float*)d_in[4];
  const float* bq = (const float*)d_in[5];
  const float* Wk = (const float*)d_in[6];
  const float* bk = (const float*)d_in[7];
  const float* Wv = (const float*)d_in[8];
  const float* bv = (const float*)d_in[9];
  float* out = (float*)d_out;

  unsigned short* kb = (unsigned short*)d_ws;            // 16 MB
  unsigned short* vb = kb + (size_t)NPOOL * H;           // 16 MB
  unsigned short* WkT = vb + (size_t)NPOOL * H;          // 128 KB
  unsigned short* WvT = WkT + H * H;                     // 128 KB
  float* qbuf = (float*)(WvT + H * H);                   // 1 MB

  prep_kernel<<<TRANS_BLOCKS + QPROJ_BLOCKS, 256, 0, stream>>>(
      Wk, Wv, WkT, WvT, enc, Wq, bq, qbuf);
  kvproj_kernel<<<512, 256, 0, stream>>>(
      soc, WkT, WvT, bk, bv, kb, vb);
  attn_kernel<<<BQ, 256, 0, stream>>>(qbuf, kb, vb, starts, ends, out);
}

// Round 10
// 56.946 us; speedup vs baseline: 4.5756x; 4.5756x over previous
//
#include <hip/hip_runtime.h>
#include <hip/hip_bf16.h>
#include <math.h>

#define H 256
#define BQ 1024
#define NPOOL 32768
#define MAXN 64

#define TRANS_BLOCKS 32    // 2 matrices x 16 tiles of 64x64
#define QPROJ_BLOCKS 256   // BQ/4

typedef __attribute__((ext_vector_type(8))) short short8;
typedef __attribute__((ext_vector_type(8))) unsigned short ushort8v;
typedef __attribute__((ext_vector_type(4))) float f32x4;

__device__ __forceinline__ unsigned short f2bf(float f) {
  unsigned int u = __float_as_uint(f);
  unsigned int r = (u + 0x7fffu + ((u >> 16) & 1u)) >> 16;
  return (unsigned short)r;
}
__device__ __forceinline__ float b2f(unsigned short u) {
  return __uint_as_float((unsigned int)u << 16);
}
__device__ __forceinline__ unsigned int cvt_pk_bf16(float a, float b) {
  unsigned int r;
  asm("v_cvt_pk_bf16_f32 %0, %1, %2" : "=v"(r) : "v"(a), "v"(b));
  return r;
}
__device__ __forceinline__ void gload16(const void* g, void* l) {
  __builtin_amdgcn_global_load_lds(
      (const __attribute__((address_space(1))) unsigned int*)g,
      (__attribute__((address_space(3))) unsigned int*)l, 16, 0, 0);
}

// ---------------------------------------------------------------------------
// prep: [0,32) transpose Wk/Wv->bf16 | [32,288) qproj (4 rows/block)
// (unchanged from r8)
// ---------------------------------------------------------------------------
__global__ __launch_bounds__(256) void prep_kernel(
    const float* __restrict__ Wk, const float* __restrict__ Wv,
    unsigned short* __restrict__ WkT, unsigned short* __restrict__ WvT,
    const float* __restrict__ enc, const float* __restrict__ Wq,
    const float* __restrict__ bq, float* __restrict__ qbuf) {
  __shared__ float smem[64 * 65];
  const int b = blockIdx.x;
  const int t = threadIdx.x;

  if (b < TRANS_BLOCKS) {
    const float* W = (b & 16) ? Wv : Wk;
    unsigned short* WT = (b & 16) ? WvT : WkT;
    const int tile = b & 15;
    const int k0 = (tile >> 2) * 64, c0 = (tile & 3) * 64;
    const int tx = t & 63, ty = t >> 6;
    float (*ls)[65] = (float(*)[65])smem;
#pragma unroll
    for (int kk = 0; kk < 16; ++kk)
      ls[tx][kk * 4 + ty] = W[(size_t)(k0 + kk * 4 + ty) * H + c0 + tx];
    __syncthreads();
#pragma unroll
    for (int cc = 0; cc < 16; ++cc) {
      const int c = cc * 4 + ty;
      WT[(size_t)(c0 + c) * H + k0 + tx] = f2bf(ls[c][tx]);
    }
  } else {
    const int bb = b - TRANS_BLOCKS;
    const int row0 = bb * 4;
    float (*xs)[H] = (float(*)[H])smem;
    {
      float4 v = *(const float4*)(enc + (size_t)(row0 + (t >> 6)) * H + (t & 63) * 4);
      *(float4*)(&xs[t >> 6][(t & 63) * 4]) = v;
    }
    __syncthreads();
    float acc[4] = {0.f, 0.f, 0.f, 0.f};
#pragma unroll 4
    for (int k = 0; k < H; ++k) {
      const float w = Wq[(size_t)k * H + t];
#pragma unroll
      for (int r = 0; r < 4; ++r) acc[r] = fmaf(xs[r][k], w, acc[r]);
    }
    const float bias = bq[t];
#pragma unroll
    for (int r = 0; r < 4; ++r)
      qbuf[(size_t)(row0 + r) * H + t] = fmaxf(acc[r] + bias, 0.f) * 0.0625f;
  }
}

// ---------------------------------------------------------------------------
// kvproj: 512 threads (8 waves -> 2 waves/SIMD), 128x128 tile, BK=64,
// double-buffered (96 KB), counted vmcnt, raw barriers.
// A: fp32 soc -> regs -> cvt_pk -> swizzled ds_write. B: global_load_lds.
// Per wave: 64x32 output quadrant (wr=wid>>2, wc=wid&3).
// ---------------------------------------------------------------------------
__global__ __launch_bounds__(512) void kvproj_kernel(
    const float* __restrict__ soc,
    const unsigned short* __restrict__ WkT,
    const unsigned short* __restrict__ WvT,
    const float* __restrict__ bk, const float* __restrict__ bv,
    unsigned short* __restrict__ kout, unsigned short* __restrict__ vout) {
  // A[2][16KB] | Bk[2][16KB] | Bv[2][16KB] = 96 KB
  __shared__ __align__(16) char LDSb[98304];
  const int t = threadIdx.x;
  const int lane = t & 63, wid = t >> 6;
  const int bid = blockIdx.x;
  const int bx = ((bid >> 4) << 3) | (bid & 7);  // 0..255
  const int by = (bid >> 3) & 1;                 // mates 8 apart (same XCD)
  const int brow = bx * 128;
  const int col0 = by * 128;

  const int srow = t >> 3;        // 0..63 (B staging)
  const int slin = t & 7;
  const int arow = t >> 2;        // 0..127 (A staging, 4 thr/row)
  const int sbase = (t & 3) * 2;  // 16B-slot base: 0,2,4,6

  f32x4 accK[2][4], accV[2][4];   // [n][m]
#pragma unroll
  for (int n = 0; n < 2; ++n)
#pragma unroll
    for (int m = 0; m < 4; ++m) { accK[n][m] = (f32x4)0.f; accV[n][m] = (f32x4)0.f; }

  const int wr = wid >> 2, wc = wid & 3;

  float4 av[4];
  const float* asrc = soc + (size_t)(brow + arow) * H + sbase * 8;

#define AREG_LOAD(kt)                                                 \
  {                                                                   \
    const float* p_ = asrc + (kt)*64;                                 \
    _Pragma("unroll") for (int s = 0; s < 4; ++s)                     \
        av[s] = *(const float4*)(p_ + s * 4);                         \
  }
#define STAGE_B(kt, pb)                                               \
  {                                                                   \
    const int k0_ = (kt)*64;                                          \
    char* bk_ = LDSb + 32768 + (pb)*16384;                            \
    char* bv_ = LDSb + 65536 + (pb)*16384;                            \
    _Pragma("unroll") for (int c = 0; c < 2; ++c) {                   \
      const int row_ = c * 64 + srow;                                 \
      const int ssrc_ = slin ^ (row_ & 7);                            \
      gload16(WkT + (size_t)(col0 + row_) * H + k0_ + ssrc_ * 8,      \
              bk_ + c * 8192 + t * 16);                               \
      gload16(WvT + (size_t)(col0 + row_) * H + k0_ + ssrc_ * 8,      \
              bv_ + c * 8192 + t * 16);                               \
    }                                                                 \
  }
#define AWRITE(pb)                                                    \
  {                                                                   \
    char* ab_ = LDSb + (pb)*16384;                                    \
    _Pragma("unroll") for (int s = 0; s < 2; ++s) {                   \
      uint4 p;                                                        \
      p.x = cvt_pk_bf16(av[2 * s].x, av[2 * s].y);                    \
      p.y = cvt_pk_bf16(av[2 * s].z, av[2 * s].w);                    \
      p.z = cvt_pk_bf16(av[2 * s + 1].x, av[2 * s + 1].y);            \
      p.w = cvt_pk_bf16(av[2 * s + 1].z, av[2 * s + 1].w);            \
      *(uint4*)(ab_ + arow * 128 + ((sbase + s) ^ (arow & 7)) * 16) = p; \
    }                                                                 \
  }

  // prologue: tile 0
  AREG_LOAD(0);                                      // vm: A0(4)
  STAGE_B(0, 0);                                     // vm: A0(4) B0(4)
  asm volatile("s_waitcnt vmcnt(4)" ::: "memory");   // A0 regs arrived
  AWRITE(0);

#pragma unroll
  for (int kt = 0; kt < 4; ++kt) {
    const int cur = kt & 1;
    if (kt < 3) {
      AREG_LOAD(kt + 1);                             // +4
      STAGE_B(kt + 1, cur ^ 1);                      // +4 -> B(kt)=oldest 4
      asm volatile("s_waitcnt vmcnt(8)" ::: "memory");  // B(kt) landed
    } else {
      asm volatile("s_waitcnt vmcnt(0)" ::: "memory");
    }
    asm volatile("s_waitcnt lgkmcnt(0)" ::: "memory");  // my A-writes drained
    __builtin_amdgcn_s_barrier();                       // half `cur` staged
    const char* Ab = LDSb + cur * 16384;
    const char* Bkb = LDSb + 32768 + cur * 16384;
    const char* Bvb = LDSb + 65536 + cur * 16384;
#pragma unroll
    for (int kk = 0; kk < 2; ++kk) {
      short8 af[4], bkf[2], bvf[2];
#pragma unroll
      for (int m = 0; m < 4; ++m) {
        const int ar = wr * 64 + m * 16 + (lane & 15);
        const int sl = (kk * 4 + (lane >> 4)) ^ (ar & 7);
        af[m] = *(const short8*)(Ab + ar * 128 + sl * 16);
      }
#pragma unroll
      for (int n = 0; n < 2; ++n) {
        const int br = wc * 32 + n * 16 + (lane & 15);
        const int sl = (kk * 4 + (lane >> 4)) ^ (br & 7);
        bkf[n] = *(const short8*)(Bkb + br * 128 + sl * 16);
        bvf[n] = *(const short8*)(Bvb + br * 128 + sl * 16);
      }
#pragma unroll
      for (int n = 0; n < 2; ++n)
#pragma unroll
        for (int m = 0; m < 4; ++m) {
          accK[n][m] = __builtin_amdgcn_mfma_f32_16x16x32_bf16(
              af[m], bkf[n], accK[n][m], 0, 0, 0);
          accV[n][m] = __builtin_amdgcn_mfma_f32_16x16x32_bf16(
              af[m], bvf[n], accV[n][m], 0, 0, 0);
        }
    }
    if (kt < 3) {
      asm volatile("s_waitcnt vmcnt(4)" ::: "memory");  // A(kt+1) regs arrived
      AWRITE(cur ^ 1);
    }
    __builtin_amdgcn_s_barrier();  // all done reading half `cur`
  }
#undef AREG_LOAD
#undef STAGE_B
#undef AWRITE

  float bkn[2], bvn[2];
#pragma unroll
  for (int n = 0; n < 2; ++n) {
    const int col = col0 + wc * 32 + n * 16 + (lane & 15);
    bkn[n] = bk[col]; bvn[n] = bv[col];
  }
#pragma unroll
  for (int n = 0; n < 2; ++n)
#pragma unroll
    for (int m = 0; m < 4; ++m) {
      const int col = col0 + wc * 32 + n * 16 + (lane & 15);
#pragma unroll
      for (int r = 0; r < 4; ++r) {
        const int row = brow + wr * 64 + m * 16 + (lane >> 4) * 4 + r;
        kout[(size_t)row * H + col] = f2bf(fmaxf(accK[n][m][r] + bkn[n], 0.f));
        vout[(size_t)row * H + col] = f2bf(fmaxf(accV[n][m][r] + bvn[n], 0.f));
      }
    }
}

// ---------------------------------------------------------------------------
// attn: per-sample sliced attention; q fp32, k/v bf16 (unchanged from r8)
// ---------------------------------------------------------------------------
__global__ __launch_bounds__(256) void attn_kernel(
    const float* __restrict__ qb, const unsigned short* __restrict__ kb,
    const unsigned short* __restrict__ vb, const int* __restrict__ starts,
    const int* __restrict__ ends, float* __restrict__ out) {
  __shared__ float sc[MAXN];
  const int row = blockIdx.x, t = threadIdx.x;
  const int lane = t & 63, wave = t >> 6;
  const int start = starts[row];
  const int len = ends[row] - start;  // 1..64

  const int qp = (lane & 31) * 8;
  const float4 qv0 = *(const float4*)(qb + (size_t)row * H + qp);
  const float4 qv1 = *(const float4*)(qb + (size_t)row * H + qp + 4);

  for (int jj = wave * 2; jj < len; jj += 8) {
    const int j0 = jj + (lane >> 5);
    if (j0 < len) {
      const ushort8v k8 =
          *(const ushort8v*)(kb + (size_t)(start + j0) * H + qp);
      float s = qv0.x * b2f(k8[0]) + qv0.y * b2f(k8[1]) +
                qv0.z * b2f(k8[2]) + qv0.w * b2f(k8[3]) +
                qv1.x * b2f(k8[4]) + qv1.y * b2f(k8[5]) +
                qv1.z * b2f(k8[6]) + qv1.w * b2f(k8[7]);
#pragma unroll
      for (int off = 16; off; off >>= 1) s += __shfl_xor(s, off, 64);
      if ((lane & 31) == 0) sc[j0] = s;
    }
  }
  __syncthreads();

  if (t < 64) {
    const float x = (t < len) ? sc[t] : -INFINITY;
    float m = x;
#pragma unroll
    for (int off = 32; off; off >>= 1) m = fmaxf(m, __shfl_xor(m, off, 64));
    const float p = (t < len) ? __expf(x - m) : 0.f;
    float ssum = p;
#pragma unroll
    for (int off = 32; off; off >>= 1) ssum += __shfl_xor(ssum, off, 64);
    sc[t] = p / ssum;
  }
  __syncthreads();

  const unsigned short* vp = vb + (size_t)start * H + t;
  float a0 = 0.f, a1 = 0.f, a2 = 0.f, a3 = 0.f;
  int j = 0;
  for (; j + 3 < len; j += 4) {
    a0 = fmaf(sc[j + 0], b2f(vp[(size_t)(j + 0) * H]), a0);
    a1 = fmaf(sc[j + 1], b2f(vp[(size_t)(j + 1) * H]), a1);
    a2 = fmaf(sc[j + 2], b2f(vp[(size_t)(j + 2) * H]), a2);
    a3 = fmaf(sc[j + 3], b2f(vp[(size_t)(j + 3) * H]), a3);
  }
  for (; j < len; ++j) a0 = fmaf(sc[j], b2f(vp[(size_t)j * H]), a0);
  out[(size_t)row * H + t] = (a0 + a1) + (a2 + a3);
}

// ---------------------------------------------------------------------------
extern "C" void kernel_launch(void* const* d_in, const int* in_sizes, int n_in,
                              void* d_out, int out_size, void* d_ws,
                              size_t ws_size, hipStream_t stream) {
  (void)in_sizes; (void)n_in; (void)out_size; (void)ws_size;
  const float* enc = (const float*)d_in[0];
  const float* soc = (const float*)d_in[1];
  const int* starts = (const int*)d_in[2];
  const int* ends = (const int*)d_in[3];
  const float* Wq = (const float*)d_in[4];
  const float* bq = (const float*)d_in[5];
  const float* Wk = (const float*)d_in[6];
  const float* bk = (const float*)d_in[7];
  const float* Wv = (const float*)d_in[8];
  const float* bv = (const float*)d_in[9];
  float* out = (float*)d_out;

  unsigned short* kb = (unsigned short*)d_ws;            // 16 MB
  unsigned short* vb = kb + (size_t)NPOOL * H;           // 16 MB
  unsigned short* WkT = vb + (size_t)NPOOL * H;          // 128 KB
  unsigned short* WvT = WkT + H * H;                     // 128 KB
  float* qbuf = (float*)(WvT + H * H);                   // 1 MB

  prep_kernel<<<TRANS_BLOCKS + QPROJ_BLOCKS, 256, 0, stream>>>(
      Wk, Wv, WkT, WvT, enc, Wq, bq, qbuf);
  kvproj_kernel<<<512, 512, 0, stream>>>(
      soc, WkT, WvT, bk, bv, kb, vb);
  attn_kernel<<<BQ, 256, 0, stream>>>(qbuf, kb, vb, starts, ends, out);
}